// Round 11
// baseline (339.827 us; speedup 1.0000x reference)
//
#include <hip/hip_runtime.h>
#include <hip/hip_fp16.h>

#define N_NODES 100000
#define N_EDGES 1600000
#define N_BUCKETS 512
#define BUCKET_NODES 196      // 512*196 = 100352 >= N_NODES
#define BKT_BLOCKS 512
#define CAPB 28               // per-(bucket,block) segment; Poisson(6.1); P(overflow)~5e-5 total
#define CAP_C 8192            // padded col slots per bucket: mean ~4700, max ~5100
#define DUMMY N_NODES         // zero feature row (byte offset DUMMY*128)

typedef unsigned short u16;

__device__ __forceinline__ float bcast_lane(float v, int k) {
    return __int_as_float(__builtin_amdgcn_readlane(__float_as_int(v), k));
}

__device__ __forceinline__ u16 f2h(float f) {
    return __half_as_ushort(__float2half_rn(f));
}

__device__ __forceinline__ void acc8(float* acc, uint4 q) {
    unsigned v[4] = {q.x, q.y, q.z, q.w};
#pragma unroll
    for (int i = 0; i < 4; ++i) {
        __half2 h = *reinterpret_cast<__half2*>(&v[i]);
        float2 f = __half22float2(h);
        acc[2 * i] += f.x;
        acc[2 * i + 1] += f.y;
    }
}

// ---- phase 1: single-pass bucket into FIXED per-(bucket,block) segments.
//      No global atomics. packed = src (17b) | local_dst (8b, <196) << 17. ----
__global__ __launch_bounds__(256) void k_bucket(const int* __restrict__ src,
                                                const int* __restrict__ dst,
                                                int* __restrict__ ebuf,
                                                u16* __restrict__ cnt16) {
    __shared__ int cnt[N_BUCKETS];
    const int CS = N_EDGES / BKT_BLOCKS;  // 3125
    int t = threadIdx.x, blk = blockIdx.x;
    int beg = blk * CS;
    for (int i = t; i < N_BUCKETS; i += 256) cnt[i] = 0;
    __syncthreads();
    for (int e = beg + t; e < beg + CS; e += 256) {
        int d = dst[e], s = src[e];
        int b = (unsigned)d / BUCKET_NODES;
        int l = atomicAdd(&cnt[b], 1);
        if (l < CAPB)
            ebuf[(b * BKT_BLOCKS + blk) * CAPB + l] = s | ((d - b * BUCKET_NODES) << 17);
    }
    __syncthreads();
    for (int i = t; i < N_BUCKETS; i += 256)
        cnt16[i * BKT_BLOCKS + blk] = (u16)(cnt[i] < CAPB ? cnt[i] : CAPB);
}

// ---- phase 2: one block (512 thr) per bucket: segment sweep x2 (count,
//      place), pad-16 scan (256-wide), col = pre-shifted byte offsets,
//      coalesced stream-out, fused xs(fp16) = z * dinv. ----
__global__ __launch_bounds__(512) void k_build(const int* __restrict__ ebuf,
                                               const u16* __restrict__ cnt16,
                                               int* __restrict__ col,
                                               int2* __restrict__ rowinfo,
                                               float* __restrict__ dinv,
                                               const float* __restrict__ z,
                                               u16* __restrict__ xs,
                                               u16* __restrict__ xs_other) {
    __shared__ int deg[BUCKET_NODES];
    __shared__ int cur[BUCKET_NODES];
    __shared__ int sm[256];
    __shared__ int cls[CAP_C];
    int b = blockIdx.x, t = threadIdx.x;
    int nb = b * BUCKET_NODES;
    int nn = N_NODES - nb;
    nn = nn < 0 ? 0 : (nn < BUCKET_NODES ? nn : BUCKET_NODES);

    for (int i = t; i < BUCKET_NODES; i += 512) deg[i] = 0;
    __syncthreads();

    // sweep 1: degree count; thread t owns run t
    int L = (int)cnt16[b * BKT_BLOCKS + t];
    const int* seg = ebuf + (b * BKT_BLOCKS + t) * CAPB;
    for (int j = 0; j < L; ++j) atomicAdd(&deg[seg[j] >> 17], 1);
    __syncthreads();

    // pad-to-16 lengths, inclusive Hillis-Steele scan over 256 slots (nn<=196)
    int v = (t < nn) ? ((deg[t] + 15) & ~15) : 0;
    if (t < 256) sm[t] = v;
    __syncthreads();
    for (int off = 1; off < 256; off <<= 1) {
        int u = (t >= off && t < 256) ? sm[t - off] : 0;
        __syncthreads();
        if (t < 256) sm[t] += u;
        __syncthreads();
    }
    int total = sm[255];
    int colbase = b * CAP_C;
    if (t < nn) {
        int off0 = sm[t] - v;
        cur[t] = off0;
        rowinfo[nb + t] = make_int2(colbase + off0, v);
        dinv[nb + t] = rsqrtf((float)deg[t] + 1.0f);
    }
    __syncthreads();
    for (int i = t; i < total; i += 512) cls[i] = DUMMY << 7;  // pads pre-filled
    __syncthreads();
    // sweep 2: place (segments L2-hot from sweep 1)
    for (int j = 0; j < L; ++j) {
        int pe = seg[j];
        int l = atomicAdd(&cur[pe >> 17], 1);
        cls[l] = (pe & 0x1FFFF) << 7;  // byte offset of src row
    }
    __syncthreads();
    for (int i = t; i < total; i += 512) col[colbase + i] = cls[i];

    // fused scale: xs(fp16) = z * dinv for this bucket's rows
    const float4* zz = (const float4*)(z + (size_t)nb * 64);
    uint2* xx = (uint2*)(xs + (size_t)nb * 64);
    for (int i = t; i < nn * 16; i += 512) {
        float4 vv = zz[i];
        float dd = rsqrtf((float)deg[i >> 4] + 1.0f);
        unsigned p0 = (unsigned)f2h(vv.x * dd) | ((unsigned)f2h(vv.y * dd) << 16);
        unsigned p1 = (unsigned)f2h(vv.z * dd) | ((unsigned)f2h(vv.w * dd) << 16);
        xx[i] = make_uint2(p0, p1);
    }
    if (b == 0 && t < 8) {  // zero dummy rows of both fp16 feature buffers
        ((uint4*)(xs + (size_t)N_NODES * 64))[t] = make_uint4(0, 0, 0, 0);
        ((uint4*)(xs_other + (size_t)N_NODES * 64))[t] = make_uint4(0, 0, 0, 0);
    }
}

// ---- gather-only aggregation: h[n] = fp16( dinv[n]*(sum_{s in row(n)} xs[s] + xs[n]) )
//      Dual node per wave + speculative iter-1: up to 8 gathers + 4 col loads
//      in flight. No W registers -> VGPR-lean. ----
__global__ __launch_bounds__(256) void k_agg(const int2* __restrict__ rowinfo,
                                             const int* __restrict__ col,
                                             const float* __restrict__ dinv,
                                             const u16* __restrict__ xs,
                                             u16* __restrict__ h) {
    const int lane = threadIdx.x & 63;
    const int eighth = lane >> 3;
    const int fh = lane & 7;
    const char* xb = (const char*)xs;
    int wave = (blockIdx.x * blockDim.x + threadIdx.x) >> 6;
    int nwaves = (gridDim.x * blockDim.x) >> 6;

    for (int n0 = wave * 2; n0 < N_NODES; n0 += nwaves * 2) {
        int u0 = __builtin_amdgcn_readfirstlane(n0);
        int u1 = u0 + 1;
        bool has1 = (u1 < N_NODES);  // wave-uniform
        int2 r0 = rowinfo[u0];
        int2 r1 = has1 ? rowinfo[u1] : r0;
        int it0 = r0.y >> 4, it1 = r1.y >> 4;  // >= 1 always

        int2 cA0 = *(const int2*)(col + r0.x + 2 * eighth);
        int2 cB0 = *(const int2*)(col + r1.x + 2 * eighth);
        int o01 = (it0 > 1) ? 16 : 0;
        int o11 = (it1 > 1) ? 16 : 0;
        int2 cA1 = *(const int2*)(col + r0.x + o01 + 2 * eighth);
        int2 cB1 = *(const int2*)(col + r1.x + o11 + 2 * eighth);
        uint4 qA0a = *(const uint4*)(xb + (unsigned)cA0.x + fh * 16);
        uint4 qA0b = *(const uint4*)(xb + (unsigned)cA0.y + fh * 16);
        uint4 qB0a = *(const uint4*)(xb + (unsigned)cB0.x + fh * 16);
        uint4 qB0b = *(const uint4*)(xb + (unsigned)cB0.y + fh * 16);
        uint4 qA1a = *(const uint4*)(xb + (unsigned)cA1.x + fh * 16);
        uint4 qA1b = *(const uint4*)(xb + (unsigned)cA1.y + fh * 16);
        uint4 qB1a = *(const uint4*)(xb + (unsigned)cB1.x + fh * 16);
        uint4 qB1b = *(const uint4*)(xb + (unsigned)cB1.y + fh * 16);

        float a0[8] = {0.f, 0.f, 0.f, 0.f, 0.f, 0.f, 0.f, 0.f};
        float a1[8] = {0.f, 0.f, 0.f, 0.f, 0.f, 0.f, 0.f, 0.f};
        acc8(a0, qA0a); acc8(a0, qA0b);
        acc8(a1, qB0a); acc8(a1, qB0b);
        if (it0 > 1) { acc8(a0, qA1a); acc8(a0, qA1b); }
        if (it1 > 1) { acc8(a1, qB1a); acc8(a1, qB1b); }

        int itm = it0 > it1 ? it0 : it1;
        for (int r = 2; r < itm; ++r) {
            int oo0 = (r < it0) ? (r << 4) : 0;
            int oo1 = (r < it1) ? (r << 4) : 0;
            int2 c0 = *(const int2*)(col + r0.x + oo0 + 2 * eighth);
            int2 c1 = *(const int2*)(col + r1.x + oo1 + 2 * eighth);
            uint4 qa = *(const uint4*)(xb + (unsigned)c0.x + fh * 16);
            uint4 qb = *(const uint4*)(xb + (unsigned)c0.y + fh * 16);
            uint4 qc = *(const uint4*)(xb + (unsigned)c1.x + fh * 16);
            uint4 qd = *(const uint4*)(xb + (unsigned)c1.y + fh * 16);
            if (r < it0) { acc8(a0, qa); acc8(a0, qb); }
            if (r < it1) { acc8(a1, qc); acc8(a1, qd); }
        }

        uint4 qs0 = *(const uint4*)(xb + (size_t)u0 * 128 + fh * 16);
        uint4 qs1 = *(const uint4*)(xb + (size_t)u1 * 128 + fh * 16);
        float d0 = dinv[u0];
        float d1 = has1 ? dinv[u1] : 0.f;

#pragma unroll
        for (int m = 8; m <= 32; m <<= 1) {
#pragma unroll
            for (int j = 0; j < 8; ++j) {
                a0[j] += __shfl_xor(a0[j], m, 64);
                a1[j] += __shfl_xor(a1[j], m, 64);
            }
        }
        float s0[8] = {0.f, 0.f, 0.f, 0.f, 0.f, 0.f, 0.f, 0.f};
        float s1[8] = {0.f, 0.f, 0.f, 0.f, 0.f, 0.f, 0.f, 0.f};
        acc8(s0, qs0); acc8(s1, qs1);
        uint4 p0, p1;
        u16* pp0 = (u16*)&p0;
        u16* pp1 = (u16*)&p1;
#pragma unroll
        for (int j = 0; j < 8; ++j) {
            pp0[j] = f2h((a0[j] + s0[j]) * d0);
            pp1[j] = f2h((a1[j] + s1[j]) * d1);
        }
        if (eighth == 0) ((uint4*)(h + (size_t)u0 * 64))[fh] = p0;
        if (has1 && eighth == 1) ((uint4*)(h + (size_t)u1 * 64))[fh] = p1;
    }
}

// ---- streamed matvec: out = epi( h @ W + b ); feature-per-lane layout. ----
__global__ __launch_bounds__(256) void k_mv(const u16* __restrict__ h,
                                            const float* __restrict__ W,
                                            const float* __restrict__ bias,
                                            const float* __restrict__ dinv,
                                            u16* __restrict__ outh,
                                            float* __restrict__ outf, int hidden) {
    const int lane = threadIdx.x & 63;
    float wcol[64];
#pragma unroll
    for (int k = 0; k < 64; ++k) wcol[k] = W[k * 64 + lane];
    const float bv = bias[lane];
    int wave = (blockIdx.x * blockDim.x + threadIdx.x) >> 6;
    int nwaves = (gridDim.x * blockDim.x) >> 6;
    for (int row = wave; row < N_NODES; row += nwaves) {
        float xv = __half2float(__ushort_as_half(h[(size_t)row * 64 + lane]));
        float o0 = bv, o1 = 0.f;
#pragma unroll
        for (int k = 0; k < 64; k += 2) {
            o0 = fmaf(bcast_lane(xv, k), wcol[k], o0);
            o1 = fmaf(bcast_lane(xv, k + 1), wcol[k + 1], o1);
        }
        float o = o0 + o1;
        if (hidden) {
            o = fmaxf(o, 0.f) * dinv[row];  // pre-scale for next layer's gather
            outh[(size_t)row * 64 + lane] = f2h(o);
        } else {
            outf[(size_t)row * 64 + lane] = o;
        }
    }
}

extern "C" void kernel_launch(void* const* d_in, const int* in_sizes, int n_in,
                              void* d_out, int out_size, void* d_ws, size_t ws_size,
                              hipStream_t stream) {
    const float* z  = (const float*)d_in[0];
    const int* src  = (const int*)d_in[1];
    const int* dst  = (const int*)d_in[2];
    const float* W1 = (const float*)d_in[3];
    const float* b1 = (const float*)d_in[4];
    const float* W2 = (const float*)d_in[5];
    const float* b2 = (const float*)d_in[6];
    const float* W3 = (const float*)d_in[7];
    const float* b3 = (const float*)d_in[8];
    float* out = (float*)d_out;

    char* p = (char*)d_ws;
    float* dinv    = (float*)p;  p += (size_t)512 << 10;
    int2*  rowinfo = (int2*)p;   p += (size_t)1 << 20;                         // 800 KB used
    u16*   cnt16   = (u16*)p;    p += (size_t)512 << 10;                       // 512 KB used
    int*   ebuf    = (int*)p;    p += (size_t)N_BUCKETS * BKT_BLOCKS * CAPB * 4;  // 29.4 MB
    int*   col     = (int*)p;    p += (size_t)N_BUCKETS * CAP_C * 4;           // 16.8 MB
    u16*   hbuf    = (u16*)p;    p += (size_t)13 << 20;                        // 12.8 MB used
    u16*   buf0    = (u16*)p;    p += (size_t)13 << 20;                        // +dummy row
    u16*   buf1    = (u16*)p;                                                  // +dummy row

    const int gA = 2048;  // 8192 waves
    const int gM = 2048;

    // ---- CSR build + fp16 scale: 2 dispatches, no memset ----
    k_bucket<<<BKT_BLOCKS, 256, 0, stream>>>(src, dst, ebuf, cnt16);
    k_build<<<N_BUCKETS, 512, 0, stream>>>(ebuf, cnt16, col, rowinfo, dinv, z, buf0, buf1);

    // ---- 3 layers: agg (gather) + mv (matvec) ----
    k_agg<<<gA, 256, 0, stream>>>(rowinfo, col, dinv, buf0, hbuf);
    k_mv <<<gM, 256, 0, stream>>>(hbuf, W1, b1, dinv, buf1, nullptr, 1);
    k_agg<<<gA, 256, 0, stream>>>(rowinfo, col, dinv, buf1, hbuf);
    k_mv <<<gM, 256, 0, stream>>>(hbuf, W2, b2, dinv, buf0, nullptr, 1);
    k_agg<<<gA, 256, 0, stream>>>(rowinfo, col, dinv, buf0, hbuf);
    k_mv <<<gM, 256, 0, stream>>>(hbuf, W3, b3, dinv, nullptr, out, 0);
}

// Round 12
// 328.777 us; speedup vs baseline: 1.0336x; 1.0336x over previous
//
#include <hip/hip_runtime.h>
#include <hip/hip_fp16.h>

#define N_NODES 100000
#define N_EDGES 1600000
#define N_BUCKETS 256
#define BUCKET_NODES 391      // 256*391 = 100096 >= N_NODES
#define BKT_BLOCKS 512
#define CAP_E 8192            // raw edges per bucket: mean 6250
#define CAP_C 12288           // padded col slots per bucket: mean ~9300
#define DUMMY N_NODES         // zero feature row (byte offset DUMMY*128)

typedef unsigned short u16;

__device__ __forceinline__ float bcast_lane(float v, int k) {
    return __int_as_float(__builtin_amdgcn_readlane(__float_as_int(v), k));
}

__device__ __forceinline__ u16 f2h(float f) {
    return __half_as_ushort(__float2half_rn(f));
}

__device__ __forceinline__ void acc8(float* acc, uint4 q) {
    unsigned v[4] = {q.x, q.y, q.z, q.w};
#pragma unroll
    for (int i = 0; i < 4; ++i) {
        __half2 h = *reinterpret_cast<__half2*>(&v[i]);
        float2 f = __half22float2(h);
        acc[2 * i] += f.x;
        acc[2 * i + 1] += f.y;
    }
}

// ---- phase 1 (R8 form): bucket edges into CONTIGUOUS per-bucket runs.
//      One global atomic per (block,bucket) reserves a run; writes are
//      coalesced within runs. packed = src (17b) | local_dst (9b) << 17. ----
__global__ __launch_bounds__(256) void k_bucket(const int* __restrict__ src,
                                                const int* __restrict__ dst,
                                                int* __restrict__ btot,
                                                int* __restrict__ ebuf) {
    __shared__ int cnt[N_BUCKETS], base_s[N_BUCKETS];
    const int CS = N_EDGES / BKT_BLOCKS;  // 3125
    int t = threadIdx.x;
    int beg = blockIdx.x * CS, end = beg + CS;
    for (int i = t; i < N_BUCKETS; i += 256) cnt[i] = 0;
    __syncthreads();
    for (int e = beg + t; e < end; e += 256)
        atomicAdd(&cnt[(unsigned)dst[e] / BUCKET_NODES], 1);
    __syncthreads();
    for (int i = t; i < N_BUCKETS; i += 256) {
        base_s[i] = atomicAdd(&btot[i], cnt[i]);
        cnt[i] = 0;  // reuse as local cursor
    }
    __syncthreads();
    for (int e = beg + t; e < end; e += 256) {
        int d = dst[e], s = src[e];
        int b = (unsigned)d / BUCKET_NODES;
        int l = atomicAdd(&cnt[b], 1);
        ebuf[b * CAP_E + base_s[b] + l] = s | ((d - b * BUCKET_NODES) << 17);
    }
}

// ---- phase 2 (R8 form, 1024 thr): LDS degree count -> dinv -> pad-16 scan ->
//      rowinfo -> LDS col bin (byte offsets) -> coalesced stream-out.
//      Fused: xs(fp16) = z * dinv; block 0 zeros both dummy rows. ----
__global__ __launch_bounds__(1024) void k_build(const int* __restrict__ btot,
                                                const int* __restrict__ ebuf,
                                                int* __restrict__ col,
                                                int2* __restrict__ rowinfo,
                                                float* __restrict__ dinv,
                                                const float* __restrict__ z,
                                                u16* __restrict__ xs,
                                                u16* __restrict__ xs_other) {
    __shared__ int deg[BUCKET_NODES];
    __shared__ int cur[BUCKET_NODES];
    __shared__ int sm[512];
    __shared__ int cls[CAP_C];
    int b = blockIdx.x, t = threadIdx.x;
    int nb = b * BUCKET_NODES;
    int nn = N_NODES - nb < BUCKET_NODES ? N_NODES - nb : BUCKET_NODES;
    int ne = btot[b];
    const int* eb = ebuf + b * CAP_E;

    for (int i = t; i < BUCKET_NODES; i += 1024) deg[i] = 0;
    __syncthreads();
    for (int e = t; e < ne; e += 1024) atomicAdd(&deg[eb[e] >> 17], 1);
    __syncthreads();

    // pad-to-16 lengths, inclusive Hillis-Steele scan over 512 slots (nn<512)
    int v = (t < nn) ? ((deg[t] + 15) & ~15) : 0;
    if (t < 512) sm[t] = v;
    __syncthreads();
    for (int off = 1; off < 512; off <<= 1) {
        int u = (t >= off && t < 512) ? sm[t - off] : 0;
        __syncthreads();
        if (t < 512) sm[t] += u;
        __syncthreads();
    }
    int total = sm[511];
    int colbase = b * CAP_C;
    if (t < nn) {
        int off0 = sm[t] - v;
        cur[t] = off0;
        rowinfo[nb + t] = make_int2(colbase + off0, v);
        dinv[nb + t] = rsqrtf((float)deg[t] + 1.0f);
    }
    __syncthreads();
    for (int i = t; i < total; i += 1024) cls[i] = DUMMY << 7;  // pads pre-filled
    __syncthreads();
    for (int e = t; e < ne; e += 1024) {
        int pe = eb[e];
        int l = atomicAdd(&cur[pe >> 17], 1);
        cls[l] = (pe & 0x1FFFF) << 7;  // byte offset of src row
    }
    __syncthreads();
    for (int i = t; i < total; i += 1024) col[colbase + i] = cls[i];

    // fused scale: xs(fp16) = z * dinv for this bucket's rows
    const float4* zz = (const float4*)(z + (size_t)nb * 64);
    uint2* xx = (uint2*)(xs + (size_t)nb * 64);
    for (int i = t; i < nn * 16; i += 1024) {
        float4 vv = zz[i];
        float dd = rsqrtf((float)deg[i >> 4] + 1.0f);
        unsigned p0 = (unsigned)f2h(vv.x * dd) | ((unsigned)f2h(vv.y * dd) << 16);
        unsigned p1 = (unsigned)f2h(vv.z * dd) | ((unsigned)f2h(vv.w * dd) << 16);
        xx[i] = make_uint2(p0, p1);
    }
    if (b == 0 && t < 8) {  // zero dummy rows of both fp16 feature buffers
        ((uint4*)(xs + (size_t)N_NODES * 64))[t] = make_uint4(0, 0, 0, 0);
        ((uint4*)(xs_other + (size_t)N_NODES * 64))[t] = make_uint4(0, 0, 0, 0);
    }
}

// ---- gather-only aggregation: h[n] = fp16( dinv[n]*(sum_{s in row(n)} xs[s] + xs[n]) )
//      Dual node per wave + speculative iter-1: up to 8 gathers + 4 col loads
//      in flight. No W registers -> VGPR-lean. ----
__global__ __launch_bounds__(256) void k_agg(const int2* __restrict__ rowinfo,
                                             const int* __restrict__ col,
                                             const float* __restrict__ dinv,
                                             const u16* __restrict__ xs,
                                             u16* __restrict__ h) {
    const int lane = threadIdx.x & 63;
    const int eighth = lane >> 3;
    const int fh = lane & 7;
    const char* xb = (const char*)xs;
    int wave = (blockIdx.x * blockDim.x + threadIdx.x) >> 6;
    int nwaves = (gridDim.x * blockDim.x) >> 6;

    for (int n0 = wave * 2; n0 < N_NODES; n0 += nwaves * 2) {
        int u0 = __builtin_amdgcn_readfirstlane(n0);
        int u1 = u0 + 1;
        bool has1 = (u1 < N_NODES);  // wave-uniform
        int2 r0 = rowinfo[u0];
        int2 r1 = has1 ? rowinfo[u1] : r0;
        int it0 = r0.y >> 4, it1 = r1.y >> 4;  // >= 1 always

        int2 cA0 = *(const int2*)(col + r0.x + 2 * eighth);
        int2 cB0 = *(const int2*)(col + r1.x + 2 * eighth);
        int o01 = (it0 > 1) ? 16 : 0;
        int o11 = (it1 > 1) ? 16 : 0;
        int2 cA1 = *(const int2*)(col + r0.x + o01 + 2 * eighth);
        int2 cB1 = *(const int2*)(col + r1.x + o11 + 2 * eighth);
        uint4 qA0a = *(const uint4*)(xb + (unsigned)cA0.x + fh * 16);
        uint4 qA0b = *(const uint4*)(xb + (unsigned)cA0.y + fh * 16);
        uint4 qB0a = *(const uint4*)(xb + (unsigned)cB0.x + fh * 16);
        uint4 qB0b = *(const uint4*)(xb + (unsigned)cB0.y + fh * 16);
        uint4 qA1a = *(const uint4*)(xb + (unsigned)cA1.x + fh * 16);
        uint4 qA1b = *(const uint4*)(xb + (unsigned)cA1.y + fh * 16);
        uint4 qB1a = *(const uint4*)(xb + (unsigned)cB1.x + fh * 16);
        uint4 qB1b = *(const uint4*)(xb + (unsigned)cB1.y + fh * 16);

        float a0[8] = {0.f, 0.f, 0.f, 0.f, 0.f, 0.f, 0.f, 0.f};
        float a1[8] = {0.f, 0.f, 0.f, 0.f, 0.f, 0.f, 0.f, 0.f};
        acc8(a0, qA0a); acc8(a0, qA0b);
        acc8(a1, qB0a); acc8(a1, qB0b);
        if (it0 > 1) { acc8(a0, qA1a); acc8(a0, qA1b); }
        if (it1 > 1) { acc8(a1, qB1a); acc8(a1, qB1b); }

        int itm = it0 > it1 ? it0 : it1;
        for (int r = 2; r < itm; ++r) {
            int oo0 = (r < it0) ? (r << 4) : 0;
            int oo1 = (r < it1) ? (r << 4) : 0;
            int2 c0 = *(const int2*)(col + r0.x + oo0 + 2 * eighth);
            int2 c1 = *(const int2*)(col + r1.x + oo1 + 2 * eighth);
            uint4 qa = *(const uint4*)(xb + (unsigned)c0.x + fh * 16);
            uint4 qb = *(const uint4*)(xb + (unsigned)c0.y + fh * 16);
            uint4 qc = *(const uint4*)(xb + (unsigned)c1.x + fh * 16);
            uint4 qd = *(const uint4*)(xb + (unsigned)c1.y + fh * 16);
            if (r < it0) { acc8(a0, qa); acc8(a0, qb); }
            if (r < it1) { acc8(a1, qc); acc8(a1, qd); }
        }

        uint4 qs0 = *(const uint4*)(xb + (size_t)u0 * 128 + fh * 16);
        uint4 qs1 = *(const uint4*)(xb + (size_t)u1 * 128 + fh * 16);
        float d0 = dinv[u0];
        float d1 = has1 ? dinv[u1] : 0.f;

#pragma unroll
        for (int m = 8; m <= 32; m <<= 1) {
#pragma unroll
            for (int j = 0; j < 8; ++j) {
                a0[j] += __shfl_xor(a0[j], m, 64);
                a1[j] += __shfl_xor(a1[j], m, 64);
            }
        }
        float s0[8] = {0.f, 0.f, 0.f, 0.f, 0.f, 0.f, 0.f, 0.f};
        float s1[8] = {0.f, 0.f, 0.f, 0.f, 0.f, 0.f, 0.f, 0.f};
        acc8(s0, qs0); acc8(s1, qs1);
        uint4 p0, p1;
        u16* pp0 = (u16*)&p0;
        u16* pp1 = (u16*)&p1;
#pragma unroll
        for (int j = 0; j < 8; ++j) {
            pp0[j] = f2h((a0[j] + s0[j]) * d0);
            pp1[j] = f2h((a1[j] + s1[j]) * d1);
        }
        if (eighth == 0) ((uint4*)(h + (size_t)u0 * 64))[fh] = p0;
        if (has1 && eighth == 1) ((uint4*)(h + (size_t)u1 * 64))[fh] = p1;
    }
}

// ---- streamed matvec: out = epi( h @ W + b ); feature-per-lane layout. ----
__global__ __launch_bounds__(256) void k_mv(const u16* __restrict__ h,
                                            const float* __restrict__ W,
                                            const float* __restrict__ bias,
                                            const float* __restrict__ dinv,
                                            u16* __restrict__ outh,
                                            float* __restrict__ outf, int hidden) {
    const int lane = threadIdx.x & 63;
    float wcol[64];
#pragma unroll
    for (int k = 0; k < 64; ++k) wcol[k] = W[k * 64 + lane];
    const float bv = bias[lane];
    int wave = (blockIdx.x * blockDim.x + threadIdx.x) >> 6;
    int nwaves = (gridDim.x * blockDim.x) >> 6;
    for (int row = wave; row < N_NODES; row += nwaves) {
        float xv = __half2float(__ushort_as_half(h[(size_t)row * 64 + lane]));
        float o0 = bv, o1 = 0.f;
#pragma unroll
        for (int k = 0; k < 64; k += 2) {
            o0 = fmaf(bcast_lane(xv, k), wcol[k], o0);
            o1 = fmaf(bcast_lane(xv, k + 1), wcol[k + 1], o1);
        }
        float o = o0 + o1;
        if (hidden) {
            o = fmaxf(o, 0.f) * dinv[row];  // pre-scale for next layer's gather
            outh[(size_t)row * 64 + lane] = f2h(o);
        } else {
            outf[(size_t)row * 64 + lane] = o;
        }
    }
}

extern "C" void kernel_launch(void* const* d_in, const int* in_sizes, int n_in,
                              void* d_out, int out_size, void* d_ws, size_t ws_size,
                              hipStream_t stream) {
    const float* z  = (const float*)d_in[0];
    const int* src  = (const int*)d_in[1];
    const int* dst  = (const int*)d_in[2];
    const float* W1 = (const float*)d_in[3];
    const float* b1 = (const float*)d_in[4];
    const float* W2 = (const float*)d_in[5];
    const float* b2 = (const float*)d_in[6];
    const float* W3 = (const float*)d_in[7];
    const float* b3 = (const float*)d_in[8];
    float* out = (float*)d_out;

    char* p = (char*)d_ws;
    float* dinv    = (float*)p;  p += (size_t)512 << 10;
    int2*  rowinfo = (int2*)p;   p += (size_t)1 << 20;                   // 800 KB used
    int*   btot    = (int*)p;    p += (size_t)4 << 10;                   // 1 KB used
    int*   ebuf    = (int*)p;    p += (size_t)N_BUCKETS * CAP_E * 4;     // 8 MB
    int*   col     = (int*)p;    p += (size_t)N_BUCKETS * CAP_C * 4;     // 12.6 MB
    u16*   hbuf    = (u16*)p;    p += (size_t)13 << 20;                  // 12.8 MB used
    u16*   buf0    = (u16*)p;    p += (size_t)13 << 20;                  // +dummy row
    u16*   buf1    = (u16*)p;                                            // +dummy row

    const int gA = 2048;  // 8192 waves
    const int gM = 2048;

    // ---- CSR build + fp16 scale ----
    hipMemsetAsync(btot, 0, N_BUCKETS * sizeof(int), stream);
    k_bucket<<<BKT_BLOCKS, 256, 0, stream>>>(src, dst, btot, ebuf);
    k_build<<<N_BUCKETS, 1024, 0, stream>>>(btot, ebuf, col, rowinfo, dinv, z, buf0, buf1);

    // ---- 3 layers: agg (gather) + mv (matvec) ----
    k_agg<<<gA, 256, 0, stream>>>(rowinfo, col, dinv, buf0, hbuf);
    k_mv <<<gM, 256, 0, stream>>>(hbuf, W1, b1, dinv, buf1, nullptr, 1);
    k_agg<<<gA, 256, 0, stream>>>(rowinfo, col, dinv, buf1, hbuf);
    k_mv <<<gM, 256, 0, stream>>>(hbuf, W2, b2, dinv, buf0, nullptr, 1);
    k_agg<<<gA, 256, 0, stream>>>(rowinfo, col, dinv, buf0, hbuf);
    k_mv <<<gM, 256, 0, stream>>>(hbuf, W3, b3, dinv, nullptr, out, 0);
}

// Round 13
// 266.565 us; speedup vs baseline: 1.2748x; 1.2334x over previous
//
#include <hip/hip_runtime.h>
#include <hip/hip_fp16.h>

#define N_NODES 100000
#define N_EDGES 1600000
#define N_BUCKETS 256
#define BUCKET_NODES 391      // 256*391 = 100096 >= N_NODES
#define BKT_BLOCKS 512
#define CAP_E 8192            // raw edges per bucket: mean 6250
#define CAP_C 12288           // padded(8) col slots per bucket: mean ~7800
#define DUMMY N_NODES         // zero feature row (byte offset DUMMY*128)

typedef unsigned short u16;
typedef _Float16 f16x8 __attribute__((ext_vector_type(8)));
typedef float f32x4 __attribute__((ext_vector_type(4)));

__device__ __forceinline__ u16 f2h(float f) {
    return __half_as_ushort(__float2half_rn(f));
}

__device__ __forceinline__ void acc8(float* acc, uint4 q) {
    unsigned v[4] = {q.x, q.y, q.z, q.w};
#pragma unroll
    for (int i = 0; i < 4; ++i) {
        __half2 h = *reinterpret_cast<__half2*>(&v[i]);
        float2 f = __half22float2(h);
        acc[2 * i] += f.x;
        acc[2 * i + 1] += f.y;
    }
}

// ---- phase 1: bucket edges into CONTIGUOUS per-bucket runs (R8 form). ----
__global__ __launch_bounds__(256) void k_bucket(const int* __restrict__ src,
                                                const int* __restrict__ dst,
                                                int* __restrict__ btot,
                                                int* __restrict__ ebuf) {
    __shared__ int cnt[N_BUCKETS], base_s[N_BUCKETS];
    const int CS = N_EDGES / BKT_BLOCKS;  // 3125
    int t = threadIdx.x;
    int beg = blockIdx.x * CS, end = beg + CS;
    for (int i = t; i < N_BUCKETS; i += 256) cnt[i] = 0;
    __syncthreads();
    for (int e = beg + t; e < end; e += 256)
        atomicAdd(&cnt[(unsigned)dst[e] / BUCKET_NODES], 1);
    __syncthreads();
    for (int i = t; i < N_BUCKETS; i += 256) {
        base_s[i] = atomicAdd(&btot[i], cnt[i]);
        cnt[i] = 0;  // reuse as local cursor
    }
    __syncthreads();
    for (int e = beg + t; e < end; e += 256) {
        int d = dst[e], s = src[e];
        int b = (unsigned)d / BUCKET_NODES;
        int l = atomicAdd(&cnt[b], 1);
        ebuf[b * CAP_E + base_s[b] + l] = s | ((d - b * BUCKET_NODES) << 17);
    }
}

// ---- phase 2: per-bucket LDS bin; PAD-8 rows; col = byte offsets; 16-entry
//      DUMMY guard after each bucket's run; fused xs(fp16) = z*dinv. ----
__global__ __launch_bounds__(1024) void k_build(const int* __restrict__ btot,
                                                const int* __restrict__ ebuf,
                                                int* __restrict__ col,
                                                int2* __restrict__ rowinfo,
                                                float* __restrict__ dinv,
                                                const float* __restrict__ z,
                                                u16* __restrict__ xs,
                                                u16* __restrict__ xs_other) {
    __shared__ int deg[BUCKET_NODES];
    __shared__ int cur[BUCKET_NODES];
    __shared__ int sm[512];
    __shared__ int cls[CAP_C];
    int b = blockIdx.x, t = threadIdx.x;
    int nb = b * BUCKET_NODES;
    int nn = N_NODES - nb < BUCKET_NODES ? N_NODES - nb : BUCKET_NODES;
    int ne = btot[b];
    const int* eb = ebuf + b * CAP_E;

    for (int i = t; i < BUCKET_NODES; i += 1024) deg[i] = 0;
    __syncthreads();
    for (int e = t; e < ne; e += 1024) atomicAdd(&deg[eb[e] >> 17], 1);
    __syncthreads();

    // pad-to-8 lengths, inclusive Hillis-Steele scan over 512 slots (nn<512)
    int v = (t < nn) ? ((deg[t] + 7) & ~7) : 0;
    if (t < 512) sm[t] = v;
    __syncthreads();
    for (int off = 1; off < 512; off <<= 1) {
        int u = (t >= off && t < 512) ? sm[t - off] : 0;
        __syncthreads();
        if (t < 512) sm[t] += u;
        __syncthreads();
    }
    int total = sm[511];
    int colbase = b * CAP_C;
    if (t < nn) {
        int off0 = sm[t] - v;
        cur[t] = off0;
        rowinfo[nb + t] = make_int2(colbase + off0, v);
        dinv[nb + t] = rsqrtf((float)deg[t] + 1.0f);
    }
    __syncthreads();
    for (int i = t; i < total; i += 1024) cls[i] = DUMMY << 7;  // pads pre-filled
    __syncthreads();
    for (int e = t; e < ne; e += 1024) {
        int pe = eb[e];
        int l = atomicAdd(&cur[pe >> 17], 1);
        cls[l] = (pe & 0x1FFFF) << 7;  // byte offset of src row
    }
    __syncthreads();
    for (int i = t; i < total; i += 1024) col[colbase + i] = cls[i];
    if (t < 16) col[colbase + total + t] = DUMMY << 7;  // guard for clamped reads

    // fused scale: xs(fp16) = z * dinv for this bucket's rows
    const float4* zz = (const float4*)(z + (size_t)nb * 64);
    uint2* xx = (uint2*)(xs + (size_t)nb * 64);
    for (int i = t; i < nn * 16; i += 1024) {
        float4 vv = zz[i];
        float dd = rsqrtf((float)deg[i >> 4] + 1.0f);
        unsigned p0 = (unsigned)f2h(vv.x * dd) | ((unsigned)f2h(vv.y * dd) << 16);
        unsigned p1 = (unsigned)f2h(vv.z * dd) | ((unsigned)f2h(vv.w * dd) << 16);
        xx[i] = make_uint2(p0, p1);
    }
    if (b == 0 && t < 8) {  // zero dummy rows of both fp16 feature buffers
        ((uint4*)(xs + (size_t)N_NODES * 64))[t] = make_uint4(0, 0, 0, 0);
        ((uint4*)(xs_other + (size_t)N_NODES * 64))[t] = make_uint4(0, 0, 0, 0);
    }
}

// ---- gather-only aggregation, pad-8 rows:
//      h[n] = fp16( dinv[n]*(sum_{s in row(n)} xs[s] + xs[n]) ).
//      Dual node per wave, 16-slot main iters (8 gathers in flight) + one
//      8-slot tail. Exhausted-node iters clamp to block 0, acc predicated. ----
__global__ __launch_bounds__(256) void k_agg(const int2* __restrict__ rowinfo,
                                             const int* __restrict__ col,
                                             const float* __restrict__ dinv,
                                             const u16* __restrict__ xs,
                                             u16* __restrict__ h) {
    const int lane = threadIdx.x & 63;
    const int eighth = lane >> 3;
    const int fh = lane & 7;
    const char* xb = (const char*)xs;
    int wave = (blockIdx.x * blockDim.x + threadIdx.x) >> 6;
    int nwaves = (gridDim.x * blockDim.x) >> 6;

    for (int n0 = wave * 2; n0 < N_NODES; n0 += nwaves * 2) {
        int u0 = __builtin_amdgcn_readfirstlane(n0);
        int u1 = u0 + 1;
        bool has1 = (u1 < N_NODES);  // wave-uniform
        int2 r0 = rowinfo[u0];
        int2 r1 = has1 ? rowinfo[u1] : r0;
        int it0 = r0.y >> 4, it1 = r1.y >> 4;
        int itm = it0 > it1 ? it0 : it1;

        float a0[8] = {0.f, 0.f, 0.f, 0.f, 0.f, 0.f, 0.f, 0.f};
        float a1[8] = {0.f, 0.f, 0.f, 0.f, 0.f, 0.f, 0.f, 0.f};
        for (int r = 0; r < itm; ++r) {
            int oo0 = (r < it0) ? (r << 4) : 0;
            int oo1 = (r < it1) ? (r << 4) : 0;
            int2 c0 = *(const int2*)(col + r0.x + oo0 + 2 * eighth);
            int2 c1 = *(const int2*)(col + r1.x + oo1 + 2 * eighth);
            uint4 qa = *(const uint4*)(xb + (unsigned)c0.x + fh * 16);
            uint4 qb = *(const uint4*)(xb + (unsigned)c0.y + fh * 16);
            uint4 qc = *(const uint4*)(xb + (unsigned)c1.x + fh * 16);
            uint4 qd = *(const uint4*)(xb + (unsigned)c1.y + fh * 16);
            if (r < it0) { acc8(a0, qa); acc8(a0, qb); }
            if (r < it1) { acc8(a1, qc); acc8(a1, qd); }
        }
        int t0 = (r0.y >> 3) & 1, t1 = (r1.y >> 3) & 1;
        if (t0 | t1) {  // 8-slot tail: one slot per lane-group
            int s0 = col[r0.x + (it0 << 4) + eighth];
            int s1 = col[r1.x + (it1 << 4) + eighth];
            uint4 q0 = *(const uint4*)(xb + (unsigned)s0 + fh * 16);
            uint4 q1 = *(const uint4*)(xb + (unsigned)s1 + fh * 16);
            if (t0) acc8(a0, q0);
            if (t1) acc8(a1, q1);
        }

        uint4 qs0 = *(const uint4*)(xb + (size_t)u0 * 128 + fh * 16);
        uint4 qs1 = *(const uint4*)(xb + (size_t)u1 * 128 + fh * 16);
        float d0 = dinv[u0];
        float d1 = has1 ? dinv[u1] : 0.f;

#pragma unroll
        for (int m = 8; m <= 32; m <<= 1) {
#pragma unroll
            for (int j = 0; j < 8; ++j) {
                a0[j] += __shfl_xor(a0[j], m, 64);
                a1[j] += __shfl_xor(a1[j], m, 64);
            }
        }
        float s0[8] = {0.f, 0.f, 0.f, 0.f, 0.f, 0.f, 0.f, 0.f};
        float s1[8] = {0.f, 0.f, 0.f, 0.f, 0.f, 0.f, 0.f, 0.f};
        acc8(s0, qs0); acc8(s1, qs1);
        uint4 p0, p1;
        u16* pp0 = (u16*)&p0;
        u16* pp1 = (u16*)&p1;
#pragma unroll
        for (int j = 0; j < 8; ++j) {
            pp0[j] = f2h((a0[j] + s0[j]) * d0);
            pp1[j] = f2h((a1[j] + s1[j]) * d1);
        }
        if (eighth == 0) ((uint4*)(h + (size_t)u0 * 64))[fh] = p0;
        if (has1 && eighth == 1) ((uint4*)(h + (size_t)u1 * 64))[fh] = p1;
    }
}

// ---- MFMA matvec: out = epi( h @ W + b ), 16-row chunks per wave.
//      mfma_f32_16x16x32_f16: A[m=lane&15][k=quad*8+j], B[k=quad*8+j][n=lane&15],
//      D[row=quad*4+reg][col=lane&15]. W converted to fp16 fragments once. ----
__global__ __launch_bounds__(256) void k_mv(const u16* __restrict__ h,
                                            const float* __restrict__ W,
                                            const float* __restrict__ bias,
                                            const float* __restrict__ dinv,
                                            u16* __restrict__ outh,
                                            float* __restrict__ outf, int hidden) {
    const int lane = threadIdx.x & 63;
    const int quad = lane >> 4;
    const int l16 = lane & 15;

    // B fragments: b[t][c] covers n = l16+16t, k = quad*8 + 32c + j
    f16x8 bfr[4][2];
#pragma unroll
    for (int t = 0; t < 4; ++t)
#pragma unroll
        for (int c = 0; c < 2; ++c)
#pragma unroll
            for (int j = 0; j < 8; ++j)
                bfr[t][c][j] = (_Float16)W[(quad * 8 + 32 * c + j) * 64 + l16 + 16 * t];
    float bv[4];
#pragma unroll
    for (int t = 0; t < 4; ++t) bv[t] = bias[l16 + 16 * t];

    int wave = (blockIdx.x * blockDim.x + threadIdx.x) >> 6;
    int nwaves = (gridDim.x * blockDim.x) >> 6;
    for (int chunk = wave; chunk < N_NODES / 16; chunk += nwaves) {
        int row0 = chunk * 16;
        const u16* hb = h + (size_t)row0 * 64;
        union { uint4 u; f16x8 f; } a0, a1;
        a0.u = *(const uint4*)(hb + l16 * 64 + quad * 8);
        a1.u = *(const uint4*)(hb + l16 * 64 + quad * 8 + 32);

        f32x4 acc[4] = {{0.f, 0.f, 0.f, 0.f}, {0.f, 0.f, 0.f, 0.f},
                        {0.f, 0.f, 0.f, 0.f}, {0.f, 0.f, 0.f, 0.f}};
#pragma unroll
        for (int t = 0; t < 4; ++t) {
            acc[t] = __builtin_amdgcn_mfma_f32_16x16x32_f16(a0.f, bfr[t][0], acc[t], 0, 0, 0);
            acc[t] = __builtin_amdgcn_mfma_f32_16x16x32_f16(a1.f, bfr[t][1], acc[t], 0, 0, 0);
        }
        float dv[4];
#pragma unroll
        for (int r = 0; r < 4; ++r) dv[r] = dinv[row0 + quad * 4 + r];
#pragma unroll
        for (int r = 0; r < 4; ++r) {
            int row = row0 + quad * 4 + r;
#pragma unroll
            for (int t = 0; t < 4; ++t) {
                float o = acc[t][r] + bv[t];
                if (hidden) {
                    o = fmaxf(o, 0.f) * dv[r];
                    outh[(size_t)row * 64 + l16 + 16 * t] = f2h(o);
                } else {
                    outf[(size_t)row * 64 + l16 + 16 * t] = o;
                }
            }
        }
    }
}

extern "C" void kernel_launch(void* const* d_in, const int* in_sizes, int n_in,
                              void* d_out, int out_size, void* d_ws, size_t ws_size,
                              hipStream_t stream) {
    const float* z  = (const float*)d_in[0];
    const int* src  = (const int*)d_in[1];
    const int* dst  = (const int*)d_in[2];
    const float* W1 = (const float*)d_in[3];
    const float* b1 = (const float*)d_in[4];
    const float* W2 = (const float*)d_in[5];
    const float* b2 = (const float*)d_in[6];
    const float* W3 = (const float*)d_in[7];
    const float* b3 = (const float*)d_in[8];
    float* out = (float*)d_out;

    char* p = (char*)d_ws;
    float* dinv    = (float*)p;  p += (size_t)512 << 10;
    int2*  rowinfo = (int2*)p;   p += (size_t)1 << 20;                   // 800 KB used
    int*   btot    = (int*)p;    p += (size_t)4 << 10;                   // 1 KB used
    int*   ebuf    = (int*)p;    p += (size_t)N_BUCKETS * CAP_E * 4;     // 8 MB
    int*   col     = (int*)p;    p += (size_t)N_BUCKETS * CAP_C * 4;     // 12.6 MB
    u16*   hbuf    = (u16*)p;    p += (size_t)13 << 20;                  // 12.8 MB used
    u16*   buf0    = (u16*)p;    p += (size_t)13 << 20;                  // +dummy row
    u16*   buf1    = (u16*)p;                                            // +dummy row

    const int gA = 2048;  // 8192 waves
    const int gM = 512;   // 2048 waves, 6250 chunks grid-stride

    // ---- CSR build + fp16 scale ----
    hipMemsetAsync(btot, 0, N_BUCKETS * sizeof(int), stream);
    k_bucket<<<BKT_BLOCKS, 256, 0, stream>>>(src, dst, btot, ebuf);
    k_build<<<N_BUCKETS, 1024, 0, stream>>>(btot, ebuf, col, rowinfo, dinv, z, buf0, buf1);

    // ---- 3 layers: agg (gather) + mv (MFMA matvec) ----
    k_agg<<<gA, 256, 0, stream>>>(rowinfo, col, dinv, buf0, hbuf);
    k_mv <<<gM, 256, 0, stream>>>(hbuf, W1, b1, dinv, buf1, nullptr, 1);
    k_agg<<<gA, 256, 0, stream>>>(rowinfo, col, dinv, buf1, hbuf);
    k_mv <<<gM, 256, 0, stream>>>(hbuf, W2, b2, dinv, buf0, nullptr, 1);
    k_agg<<<gA, 256, 0, stream>>>(rowinfo, col, dinv, buf0, hbuf);
    k_mv <<<gM, 256, 0, stream>>>(hbuf, W3, b3, dinv, nullptr, out, 0);
}